// Round 1
// baseline (498.542 us; speedup 1.0000x reference)
//
#include <hip/hip_runtime.h>
#include <hip/hip_bf16.h>

// Problem constants
#define B_  16
#define C_  6
#define T_  512
#define S_  8
#define F_  512
#define H_  8
#define DK_ 64

__device__ __forceinline__ ushort f2bf(float f) {
    __hip_bfloat16 h = __float2bfloat16(f);
    return *reinterpret_cast<ushort*>(&h);
}
__device__ __forceinline__ float bf2f(__hip_bfloat16 h) {
    return __bfloat162float(h);
}

// ---------------------------------------------------------------------------
// 512x512 transpose (for coalesced GEMM B-operand reads)
// grid (16,16), block (32,8)
__global__ void transpose512(const float* __restrict__ src, float* __restrict__ dst) {
    __shared__ float tile[32][33];
    int bx = blockIdx.x * 32, by = blockIdx.y * 32;
    int tx = threadIdx.x, ty = threadIdx.y;
    for (int i = 0; i < 32; i += 8)
        tile[ty + i][tx] = src[(long)(by + ty + i) * 512 + bx + tx];
    __syncthreads();
    for (int i = 0; i < 32; i += 8)
        dst[(long)(bx + ty + i) * 512 + by + tx] = tile[tx][ty + i];
}

// ---------------------------------------------------------------------------
// K/V projections: k = key @ Wk.T + bk, v = value @ Wv.T + bv
// grid = B*S = 128 blocks, 512 threads
__global__ void kv_proj(const float* __restrict__ key, const float* __restrict__ value,
                        const float* __restrict__ WkT, const float* __restrict__ WvT,
                        const float* __restrict__ bk, const float* __restrict__ bv,
                        float* __restrict__ kout, float* __restrict__ vout) {
    int row = blockIdx.x;      // b*S + s
    int j = threadIdx.x;       // 0..511
    __shared__ float krow[512];
    __shared__ float vrow[512];
    krow[j] = key[(long)row * 512 + j];
    vrow[j] = value[(long)row * 512 + j];
    __syncthreads();
    float ak = bk[j], av = bv[j];
    for (int f = 0; f < 512; ++f) {
        ak += krow[f] * WkT[(long)f * 512 + j];   // coalesced over j
        av += vrow[f] * WvT[(long)f * 512 + j];
    }
    kout[(long)row * 512 + j] = ak;
    vout[(long)row * 512 + j] = av;
}

// ---------------------------------------------------------------------------
// Tiled fp32 GEMM:  out[m, n] = sum_k A[m, k] * W[n, k] + bias[n]
// BT is pre-transposed W (BT[k*512+n] = W[n*512+k]). N = K = 512 fixed.
// BM=BN=128, BK=8, 256 threads, 8x8 per thread (split 4+4 rows/cols).
// PERM=1: logical row m = ((b*T+t)*C+c) maps to query source row (b,c,t).
// OUTBF=1: output rounded to bf16 (ushort), else fp32.
template <int PERM, int OUTBF>
__global__ __launch_bounds__(256) void gemm_tn(const float* __restrict__ A,
                                               const float* __restrict__ BT,
                                               const float* __restrict__ bias,
                                               void* __restrict__ out, int M) {
    __shared__ float As[8][132];
    __shared__ float Bs[8][132];
    const int tid = threadIdx.x;
    const int bm = blockIdx.x * 128;
    const int bn = blockIdx.y * 128;
    const int tx = tid & 15;
    const int ty = tid >> 4;

    // A staging: each thread loads one float4 (row = tid/2, k-offset = (tid&1)*4)
    const int arow = tid >> 1;
    const int ak   = (tid & 1) << 2;
    int m = bm + arow;
    long asrc;
    if (PERM) {
        int c  = m % C_;
        int bt = m / C_;
        int b  = bt >> 9;      // / T_
        int t  = bt & 511;     // % T_
        asrc = ((long)((b * C_ + c) * T_ + t)) * 512;
    } else {
        asrc = (long)m * 512;
    }
    // B staging: kk = tid/32, n-offset = (tid&31)*4
    const int bkk = tid >> 5;
    const int bnq = (tid & 31) << 2;

    float acc[8][8];
#pragma unroll
    for (int i = 0; i < 8; ++i)
#pragma unroll
        for (int j = 0; j < 8; ++j) acc[i][j] = 0.f;

    for (int k0 = 0; k0 < 512; k0 += 8) {
        float4 av = *(const float4*)(A + asrc + k0 + ak);
        float4 bv = *(const float4*)(BT + (long)(k0 + bkk) * 512 + bn + bnq);
        As[ak + 0][arow] = av.x;
        As[ak + 1][arow] = av.y;
        As[ak + 2][arow] = av.z;
        As[ak + 3][arow] = av.w;
        *(float4*)&Bs[bkk][bnq] = bv;
        __syncthreads();
#pragma unroll
        for (int kk = 0; kk < 8; ++kk) {
            float4 a0 = *(const float4*)&As[kk][ty * 4];
            float4 a1 = *(const float4*)&As[kk][64 + ty * 4];
            float4 b0 = *(const float4*)&Bs[kk][tx * 4];
            float4 b1 = *(const float4*)&Bs[kk][64 + tx * 4];
            float a[8] = {a0.x, a0.y, a0.z, a0.w, a1.x, a1.y, a1.z, a1.w};
            float b[8] = {b0.x, b0.y, b0.z, b0.w, b1.x, b1.y, b1.z, b1.w};
#pragma unroll
            for (int i = 0; i < 8; ++i)
#pragma unroll
                for (int j = 0; j < 8; ++j) acc[i][j] += a[i] * b[j];
        }
        __syncthreads();
    }

    float bl[4], bh[4];
#pragma unroll
    for (int j = 0; j < 4; ++j) {
        bl[j] = bias[bn + tx * 4 + j];
        bh[j] = bias[bn + 64 + tx * 4 + j];
    }
#pragma unroll
    for (int i = 0; i < 8; ++i) {
        int gr = bm + ((i < 4) ? (ty * 4 + i) : (64 + ty * 4 + (i - 4)));
        if (OUTBF) {
            ushort4 p0, p1;
            p0.x = f2bf(acc[i][0] + bl[0]);
            p0.y = f2bf(acc[i][1] + bl[1]);
            p0.z = f2bf(acc[i][2] + bl[2]);
            p0.w = f2bf(acc[i][3] + bl[3]);
            p1.x = f2bf(acc[i][4] + bh[0]);
            p1.y = f2bf(acc[i][5] + bh[1]);
            p1.z = f2bf(acc[i][6] + bh[2]);
            p1.w = f2bf(acc[i][7] + bh[3]);
            ushort* op = (ushort*)out + (long)gr * 512;
            *(ushort4*)(op + bn + tx * 4) = p0;
            *(ushort4*)(op + bn + 64 + tx * 4) = p1;
        } else {
            float4 f0 = make_float4(acc[i][0] + bl[0], acc[i][1] + bl[1],
                                    acc[i][2] + bl[2], acc[i][3] + bl[3]);
            float4 f1 = make_float4(acc[i][4] + bh[0], acc[i][5] + bh[1],
                                    acc[i][6] + bh[2], acc[i][7] + bh[3]);
            float* op = (float*)out + (long)gr * 512;
            *(float4*)(op + bn + tx * 4) = f0;
            *(float4*)(op + bn + 64 + tx * 4) = f1;
        }
    }
    (void)M;
}

// ---------------------------------------------------------------------------
// q1[b,t,f] = mean over c of q[b,t,c,f]   (q stored bf16, rows ordered (b,t,c))
__global__ void q1_mean(const __hip_bfloat16* __restrict__ qbf, float* __restrict__ q1) {
    int idx = blockIdx.x * 256 + threadIdx.x;      // over B*T*512 = 4.2M
    if (idx >= B_ * T_ * 512) return;
    int bt = idx >> 9;
    int f  = idx & 511;
    float s = 0.f;
#pragma unroll
    for (int c = 0; c < C_; ++c)
        s += bf2f(qbf[((long)(bt * C_ + c) << 9) + f]);
    q1[idx] = s * (1.0f / C_);
}

// ---------------------------------------------------------------------------
// Stage 1: scores = q1·k / 8, masked softmax over s, pc = attn @ v
// grid = B*T = 8192, block = 64 (one wave). lane = h*8 + s.
__global__ __launch_bounds__(64) void stage1(const float* __restrict__ q1,
                                             const float* __restrict__ kproj,
                                             const float* __restrict__ vproj,
                                             const int* __restrict__ mask,
                                             float* __restrict__ pc) {
    int bt = blockIdx.x;
    int b = bt >> 9, t = bt & 511;
    int lane = threadIdx.x;
    int h = lane >> 3, s = lane & 7;

    const float* qrow = q1 + (long)bt * 512 + h * 64;
    const float* krow = kproj + (long)(b * S_ + s) * 512 + h * 64;
    float sc = 0.f;
#pragma unroll 8
    for (int d = 0; d < 64; ++d) sc += qrow[d] * krow[d];
    sc *= 0.125f;  // 1/sqrt(64)
    int mk = mask[((long)b * T_ + t) * S_ + s];
    if (mk == 0) sc = -1e30f;

    float mx = sc;
    for (int off = 1; off < 8; off <<= 1) mx = fmaxf(mx, __shfl_xor(mx, off));
    float e = __expf(sc - mx);
    float sum = e;
    for (int off = 1; off < 8; off <<= 1) sum += __shfl_xor(sum, off);
    float attn = e / sum;
    if (mk == 0) attn = 0.f;

    // pc[f = i*64 + lane], h-index of output = i
#pragma unroll
    for (int i = 0; i < 8; ++i) {
        float acc = 0.f;
#pragma unroll
        for (int s2 = 0; s2 < 8; ++s2) {
            float a = __shfl(attn, i * 8 + s2);
            acc += a * vproj[(long)(b * S_ + s2) * 512 + i * 64 + lane];
        }
        pc[(long)bt * 512 + i * 64 + lane] = acc;
    }
}

// ---------------------------------------------------------------------------
// Stage 2: ss[h,c] = pc·q_c / 8, softmax over c, x = attn2-weighted sum of q_c
// grid = B*T = 8192, block = 64.
__global__ __launch_bounds__(64) void stage2(const float* __restrict__ pc,
                                             const __hip_bfloat16* __restrict__ qbf,
                                             float* __restrict__ x) {
    int bt = blockIdx.x;
    int lane = threadIdx.x;
    __shared__ float ssl[48];
    __shared__ float a2l[48];

    if (lane < 48) {
        int h = lane / 6, c = lane % 6;
        const float* pr = pc + (long)bt * 512 + h * 64;
        const __hip_bfloat16* qr = qbf + (long)(bt * C_ + c) * 512 + h * 64;
        float acc = 0.f;
#pragma unroll 8
        for (int d = 0; d < 64; ++d) acc += pr[d] * bf2f(qr[d]);
        ssl[lane] = acc * 0.125f;
    }
    __syncthreads();
    if (lane < 8) {
        float mx = -1e30f;
#pragma unroll
        for (int c = 0; c < 6; ++c) mx = fmaxf(mx, ssl[lane * 6 + c]);
        float e[6];
        float sum = 0.f;
#pragma unroll
        for (int c = 0; c < 6; ++c) {
            e[c] = __expf(ssl[lane * 6 + c] - mx);
            sum += e[c];
        }
        float inv = 1.0f / sum;
#pragma unroll
        for (int c = 0; c < 6; ++c) a2l[lane * 6 + c] = e[c] * inv;
    }
    __syncthreads();
#pragma unroll
    for (int i = 0; i < 8; ++i) {
        float acc = 0.f;
#pragma unroll
        for (int c = 0; c < 6; ++c)
            acc += a2l[i * 6 + c] * bf2f(qbf[(long)(bt * C_ + c) * 512 + i * 64 + lane]);
        x[(long)bt * 512 + i * 64 + lane] = acc;
    }
}

// ---------------------------------------------------------------------------
extern "C" void kernel_launch(void* const* d_in, const int* in_sizes, int n_in,
                              void* d_out, int out_size, void* d_ws, size_t ws_size,
                              hipStream_t stream) {
    const float* query = (const float*)d_in[0];
    const float* key   = (const float*)d_in[1];
    const float* value = (const float*)d_in[2];
    const int*   mask  = (const int*)d_in[3];
    const float* Wq = (const float*)d_in[4];
    const float* bq = (const float*)d_in[5];
    const float* Wk = (const float*)d_in[6];
    const float* bk = (const float*)d_in[7];
    const float* Wv = (const float*)d_in[8];
    const float* bv = (const float*)d_in[9];
    const float* Wo = (const float*)d_in[10];
    const float* bo = (const float*)d_in[11];
    float* out = (float*)d_out;

    // Workspace layout (bytes):
    //   0        : WqT (1MB), WkT (1MB), WvT (1MB), WoT (1MB)
    //   4MB      : kproj (256KB), vproj (256KB)
    //   4.5MB    : q bf16 (B*T*C*512 * 2 = 48MB)
    //   ...      : q1 (16MB fp32), pc (16MB fp32), x (16MB fp32)
    // total ~101MB
    char* ws = (char*)d_ws;
    float* WqT = (float*)(ws + 0);
    float* WkT = (float*)(ws + (1u << 20));
    float* WvT = (float*)(ws + (2u << 20));
    float* WoT = (float*)(ws + (3u << 20));
    float* kproj = (float*)(ws + (4u << 20));
    float* vproj = (float*)(ws + (4u << 20) + 262144u);
    __hip_bfloat16* qbf = (__hip_bfloat16*)(ws + 4718592u);
    float* q1 = (float*)(ws + 55050240u);
    float* pc = (float*)(ws + 71827456u);
    float* x  = (float*)(ws + 88604672u);

    dim3 tb(32, 8), tg(16, 16);
    transpose512<<<tg, tb, 0, stream>>>(Wq, WqT);
    transpose512<<<tg, tb, 0, stream>>>(Wk, WkT);
    transpose512<<<tg, tb, 0, stream>>>(Wv, WvT);
    transpose512<<<tg, tb, 0, stream>>>(Wo, WoT);

    kv_proj<<<B_ * S_, 512, 0, stream>>>(key, value, WkT, WvT, bk, bv, kproj, vproj);

    // q projection: M = B*T*C = 49152 rows (ordered (b,t,c)), bf16 out
    gemm_tn<1, 1><<<dim3(384, 4), 256, 0, stream>>>(query, WqT, bq, qbf, 49152);

    q1_mean<<<16384, 256, 0, stream>>>(qbf, q1);

    stage1<<<B_ * T_, 64, 0, stream>>>(q1, kproj, vproj, mask, pc);
    stage2<<<B_ * T_, 64, 0, stream>>>(pc, qbf, x);

    // output projection: M = B*T = 8192, fp32 out
    gemm_tn<0, 0><<<dim3(64, 4), 256, 0, stream>>>(x, WoT, bo, out, 8192);

    (void)in_sizes; (void)n_in; (void)out_size; (void)ws_size;
}

// Round 2
// 280.061 us; speedup vs baseline: 1.7801x; 1.7801x over previous
//
#include <hip/hip_runtime.h>
#include <hip/hip_bf16.h>

// Problem constants
#define B_  16
#define C_  6
#define T_  512
#define S_  8
#define F_  512
#define H_  8
#define DK_ 64

typedef __attribute__((ext_vector_type(8))) short bf16x8;
typedef __attribute__((ext_vector_type(4))) float f32x4;

__device__ __forceinline__ ushort f2bf(float f) {
    __hip_bfloat16 h = __float2bfloat16(f);
    return *reinterpret_cast<ushort*>(&h);
}
__device__ __forceinline__ float bf2f(__hip_bfloat16 h) {
    return __bfloat162float(h);
}

// ---------------------------------------------------------------------------
// 512x512 transpose (for fp32 GEMM / kv_proj coalesced B-reads)
__global__ void transpose512(const float* __restrict__ src, float* __restrict__ dst) {
    __shared__ float tile[32][33];
    int bx = blockIdx.x * 32, by = blockIdx.y * 32;
    int tx = threadIdx.x, ty = threadIdx.y;
    for (int i = 0; i < 32; i += 8)
        tile[ty + i][tx] = src[(long)(by + ty + i) * 512 + bx + tx];
    __syncthreads();
    for (int i = 0; i < 32; i += 8)
        dst[(long)(bx + ty + i) * 512 + by + tx] = tile[tx][ty + i];
}

// fp32 -> bf16 elementwise (512x512 weights), grid 256 x 256 threads
__global__ void convert_bf16_512(const float* __restrict__ src, ushort* __restrict__ dst) {
    int i = (blockIdx.x * 256 + threadIdx.x) * 4;
    float4 v = *(const float4*)(src + i);
    ushort4 o;
    o.x = f2bf(v.x); o.y = f2bf(v.y); o.z = f2bf(v.z); o.w = f2bf(v.w);
    *(ushort4*)(dst + i) = o;
}

// ---------------------------------------------------------------------------
// K/V projections: k = key @ Wk.T + bk, v = value @ Wv.T + bv
__global__ void kv_proj(const float* __restrict__ key, const float* __restrict__ value,
                        const float* __restrict__ WkT, const float* __restrict__ WvT,
                        const float* __restrict__ bk, const float* __restrict__ bv,
                        float* __restrict__ kout, float* __restrict__ vout) {
    int row = blockIdx.x;      // b*S + s
    int j = threadIdx.x;       // 0..511
    __shared__ float krow[512];
    __shared__ float vrow[512];
    krow[j] = key[(long)row * 512 + j];
    vrow[j] = value[(long)row * 512 + j];
    __syncthreads();
    float ak = bk[j], av = bv[j];
    for (int f = 0; f < 512; ++f) {
        ak += krow[f] * WkT[(long)f * 512 + j];
        av += vrow[f] * WvT[(long)f * 512 + j];
    }
    kout[(long)row * 512 + j] = ak;
    vout[(long)row * 512 + j] = av;
}

// ---------------------------------------------------------------------------
// MFMA bf16 GEMM for the Q projection.
// out[m,n] = sum_k A[m,k] * W[n,k] + bias[n]; A fp32 (PERM row map), W bf16 [n][k].
// M = 49152, N = K = 512. 128x128 tile, BK=64, 4 waves (2x2), 64x64/wave.
// LDS: As/Ws stored [row][64] bf16 with 16B-chunk XOR swizzle (chunk ^= row&7)
// so stride-128B fragment ds_read_b128 is conflict-free (T2).
// XCD swizzle (T1): 1536 blocks, bijective since 1536 % 8 == 0.
__global__ __launch_bounds__(256) void qproj_mfma(const float* __restrict__ A,
                                                  const ushort* __restrict__ Wbf,
                                                  const float* __restrict__ bias,
                                                  ushort* __restrict__ out) {
    __shared__ ushort As[8192];   // 128 rows x 64 bf16 (16 KB)
    __shared__ ushort Ws[8192];

    const int bid = blockIdx.x;
    const int swz = (bid & 7) * 192 + (bid >> 3);   // XCD-contiguous chunks
    const int bm = (swz >> 2) * 128;                // 384 m-panels
    const int bn = (swz & 3) * 128;                 // 4 n-panels

    const int tid  = threadIdx.x;
    const int lane = tid & 63;
    const int wv   = tid >> 6;
    const int wm   = (wv >> 1) * 64;
    const int wn   = (wv & 1) * 64;
    const int ln15 = lane & 15;
    const int ln16 = lane >> 4;

    // staging slots: thread -> (row r0+32i, 8-elem k-chunk kc)
    const int kc = tid & 7;
    const int r0 = tid >> 3;

    long asrc[4];
#pragma unroll
    for (int i = 0; i < 4; ++i) {
        int m  = bm + r0 + 32 * i;          // logical row, (b,t,c) order
        int c  = m % 6;
        int bt = m / 6;
        int b  = bt >> 9;
        int t  = bt & 511;
        asrc[i] = ((long)(b * 6 + c) * 512 + t) * 512;   // query row (b,c,t)
    }
    const long wsrc0 = (long)(bn + r0) * 512 + kc * 8;

    float4 ra[4][2];
    uint4  rw[4];

    auto load_tile = [&](int k0) {
#pragma unroll
        for (int i = 0; i < 4; ++i) {
            const float* ap = A + asrc[i] + k0 + kc * 8;
            ra[i][0] = *(const float4*)ap;
            ra[i][1] = *(const float4*)(ap + 4);
            rw[i] = *(const uint4*)(Wbf + wsrc0 + (long)(32 * i) * 512 + k0);
        }
    };
    auto write_tile = [&]() {
#pragma unroll
        for (int i = 0; i < 4; ++i) {
            int r = r0 + 32 * i;
            int idx = r * 64 + ((kc ^ (r & 7)) << 3);
            uint4 pk;
            pk.x = (uint)f2bf(ra[i][0].x) | ((uint)f2bf(ra[i][0].y) << 16);
            pk.y = (uint)f2bf(ra[i][0].z) | ((uint)f2bf(ra[i][0].w) << 16);
            pk.z = (uint)f2bf(ra[i][1].x) | ((uint)f2bf(ra[i][1].y) << 16);
            pk.w = (uint)f2bf(ra[i][1].z) | ((uint)f2bf(ra[i][1].w) << 16);
            *(uint4*)&As[idx] = pk;
            *(uint4*)&Ws[idx] = rw[i];
        }
    };

    f32x4 acc[4][4] = {};

    load_tile(0);
    for (int kt = 0; kt < 8; ++kt) {
        write_tile();
        __syncthreads();
        if (kt < 7) load_tile((kt + 1) * 64);   // T14: issue next loads early
#pragma unroll
        for (int kj = 0; kj < 2; ++kj) {
            bf16x8 af[4], bfv[4];
#pragma unroll
            for (int mi = 0; mi < 4; ++mi) {
                int row = wm + mi * 16 + ln15;
                int ch  = kj * 4 + ln16;
                af[mi] = *(const bf16x8*)&As[row * 64 + ((ch ^ (row & 7)) << 3)];
            }
#pragma unroll
            for (int ni = 0; ni < 4; ++ni) {
                int row = wn + ni * 16 + ln15;
                int ch  = kj * 4 + ln16;
                bfv[ni] = *(const bf16x8*)&Ws[row * 64 + ((ch ^ (row & 7)) << 3)];
            }
#pragma unroll
            for (int mi = 0; mi < 4; ++mi)
#pragma unroll
                for (int ni = 0; ni < 4; ++ni)
                    acc[mi][ni] = __builtin_amdgcn_mfma_f32_16x16x32_bf16(
                        af[mi], bfv[ni], acc[mi][ni], 0, 0, 0);
        }
        __syncthreads();
    }

    // Epilogue: C/D layout col = lane&15, row = (lane>>4)*4 + j
    float bsv[4];
#pragma unroll
    for (int ni = 0; ni < 4; ++ni)
        bsv[ni] = bias[bn + wn + ni * 16 + ln15];

#pragma unroll
    for (int mi = 0; mi < 4; ++mi) {
#pragma unroll
        for (int j = 0; j < 4; ++j) {
            long m = bm + wm + mi * 16 + ln16 * 4 + j;
            ushort* op = out + m * 512 + bn + wn + ln15;
#pragma unroll
            for (int ni = 0; ni < 4; ++ni)
                op[ni * 16] = f2bf(acc[mi][ni][j] + bsv[ni]);
        }
    }
}

// ---------------------------------------------------------------------------
// Tiled fp32 GEMM (kept for the output projection; protects absmax budget)
template <int PERM, int OUTBF>
__global__ __launch_bounds__(256) void gemm_tn(const float* __restrict__ A,
                                               const float* __restrict__ BT,
                                               const float* __restrict__ bias,
                                               void* __restrict__ out, int M) {
    __shared__ float As[8][132];
    __shared__ float Bs[8][132];
    const int tid = threadIdx.x;
    const int bm = blockIdx.x * 128;
    const int bn = blockIdx.y * 128;
    const int tx = tid & 15;
    const int ty = tid >> 4;

    const int arow = tid >> 1;
    const int ak   = (tid & 1) << 2;
    int m = bm + arow;
    long asrc;
    if (PERM) {
        int c  = m % C_;
        int bt = m / C_;
        int b  = bt >> 9;
        int t  = bt & 511;
        asrc = ((long)((b * C_ + c) * T_ + t)) * 512;
    } else {
        asrc = (long)m * 512;
    }
    const int bkk = tid >> 5;
    const int bnq = (tid & 31) << 2;

    float acc[8][8];
#pragma unroll
    for (int i = 0; i < 8; ++i)
#pragma unroll
        for (int j = 0; j < 8; ++j) acc[i][j] = 0.f;

    for (int k0 = 0; k0 < 512; k0 += 8) {
        float4 av = *(const float4*)(A + asrc + k0 + ak);
        float4 bv = *(const float4*)(BT + (long)(k0 + bkk) * 512 + bn + bnq);
        As[ak + 0][arow] = av.x;
        As[ak + 1][arow] = av.y;
        As[ak + 2][arow] = av.z;
        As[ak + 3][arow] = av.w;
        *(float4*)&Bs[bkk][bnq] = bv;
        __syncthreads();
#pragma unroll
        for (int kk = 0; kk < 8; ++kk) {
            float4 a0 = *(const float4*)&As[kk][ty * 4];
            float4 a1 = *(const float4*)&As[kk][64 + ty * 4];
            float4 b0 = *(const float4*)&Bs[kk][tx * 4];
            float4 b1 = *(const float4*)&Bs[kk][64 + tx * 4];
            float a[8] = {a0.x, a0.y, a0.z, a0.w, a1.x, a1.y, a1.z, a1.w};
            float b[8] = {b0.x, b0.y, b0.z, b0.w, b1.x, b1.y, b1.z, b1.w};
#pragma unroll
            for (int i = 0; i < 8; ++i)
#pragma unroll
                for (int j = 0; j < 8; ++j) acc[i][j] += a[i] * b[j];
        }
        __syncthreads();
    }

    float bl[4], bh[4];
#pragma unroll
    for (int j = 0; j < 4; ++j) {
        bl[j] = bias[bn + tx * 4 + j];
        bh[j] = bias[bn + 64 + tx * 4 + j];
    }
#pragma unroll
    for (int i = 0; i < 8; ++i) {
        int gr = bm + ((i < 4) ? (ty * 4 + i) : (64 + ty * 4 + (i - 4)));
        if (OUTBF) {
            ushort4 p0, p1;
            p0.x = f2bf(acc[i][0] + bl[0]);
            p0.y = f2bf(acc[i][1] + bl[1]);
            p0.z = f2bf(acc[i][2] + bl[2]);
            p0.w = f2bf(acc[i][3] + bl[3]);
            p1.x = f2bf(acc[i][4] + bh[0]);
            p1.y = f2bf(acc[i][5] + bh[1]);
            p1.z = f2bf(acc[i][6] + bh[2]);
            p1.w = f2bf(acc[i][7] + bh[3]);
            ushort* op = (ushort*)out + (long)gr * 512;
            *(ushort4*)(op + bn + tx * 4) = p0;
            *(ushort4*)(op + bn + 64 + tx * 4) = p1;
        } else {
            float4 f0 = make_float4(acc[i][0] + bl[0], acc[i][1] + bl[1],
                                    acc[i][2] + bl[2], acc[i][3] + bl[3]);
            float4 f1 = make_float4(acc[i][4] + bh[0], acc[i][5] + bh[1],
                                    acc[i][6] + bh[2], acc[i][7] + bh[3]);
            float* op = (float*)out + (long)gr * 512;
            *(float4*)(op + bn + tx * 4) = f0;
            *(float4*)(op + bn + 64 + tx * 4) = f1;
        }
    }
    (void)M;
}

// ---------------------------------------------------------------------------
// q1[b,t,f] = mean over c of q[b,t,c,f]
__global__ void q1_mean(const __hip_bfloat16* __restrict__ qbf, float* __restrict__ q1) {
    int idx = blockIdx.x * 256 + threadIdx.x;
    if (idx >= B_ * T_ * 512) return;
    int bt = idx >> 9;
    int f  = idx & 511;
    float s = 0.f;
#pragma unroll
    for (int c = 0; c < C_; ++c)
        s += bf2f(qbf[((long)(bt * C_ + c) << 9) + f]);
    q1[idx] = s * (1.0f / C_);
}

// ---------------------------------------------------------------------------
// Stage 1: scores = q1·k / 8, masked softmax over s, pc = attn @ v
__global__ __launch_bounds__(64) void stage1(const float* __restrict__ q1,
                                             const float* __restrict__ kproj,
                                             const float* __restrict__ vproj,
                                             const int* __restrict__ mask,
                                             float* __restrict__ pc) {
    int bt = blockIdx.x;
    int b = bt >> 9, t = bt & 511;
    int lane = threadIdx.x;
    int h = lane >> 3, s = lane & 7;

    const float* qrow = q1 + (long)bt * 512 + h * 64;
    const float* krow = kproj + (long)(b * S_ + s) * 512 + h * 64;
    float sc = 0.f;
#pragma unroll 8
    for (int d = 0; d < 64; ++d) sc += qrow[d] * krow[d];
    sc *= 0.125f;
    int mk = mask[((long)b * T_ + t) * S_ + s];
    if (mk == 0) sc = -1e30f;

    float mx = sc;
    for (int off = 1; off < 8; off <<= 1) mx = fmaxf(mx, __shfl_xor(mx, off));
    float e = __expf(sc - mx);
    float sum = e;
    for (int off = 1; off < 8; off <<= 1) sum += __shfl_xor(sum, off);
    float attn = e / sum;
    if (mk == 0) attn = 0.f;

#pragma unroll
    for (int i = 0; i < 8; ++i) {
        float acc = 0.f;
#pragma unroll
        for (int s2 = 0; s2 < 8; ++s2) {
            float a = __shfl(attn, i * 8 + s2);
            acc += a * vproj[(long)(b * S_ + s2) * 512 + i * 64 + lane];
        }
        pc[(long)bt * 512 + i * 64 + lane] = acc;
    }
}

// ---------------------------------------------------------------------------
// Stage 2: ss[h,c] = pc·q_c / 8, softmax over c, x = attn2-weighted sum of q_c
__global__ __launch_bounds__(64) void stage2(const float* __restrict__ pc,
                                             const __hip_bfloat16* __restrict__ qbf,
                                             float* __restrict__ x) {
    int bt = blockIdx.x;
    int lane = threadIdx.x;
    __shared__ float ssl[48];
    __shared__ float a2l[48];

    if (lane < 48) {
        int h = lane / 6, c = lane % 6;
        const float* pr = pc + (long)bt * 512 + h * 64;
        const __hip_bfloat16* qr = qbf + (long)(bt * C_ + c) * 512 + h * 64;
        float acc = 0.f;
#pragma unroll 8
        for (int d = 0; d < 64; ++d) acc += pr[d] * bf2f(qr[d]);
        ssl[lane] = acc * 0.125f;
    }
    __syncthreads();
    if (lane < 8) {
        float mx = -1e30f;
#pragma unroll
        for (int c = 0; c < 6; ++c) mx = fmaxf(mx, ssl[lane * 6 + c]);
        float e[6];
        float sum = 0.f;
#pragma unroll
        for (int c = 0; c < 6; ++c) {
            e[c] = __expf(ssl[lane * 6 + c] - mx);
            sum += e[c];
        }
        float inv = 1.0f / sum;
#pragma unroll
        for (int c = 0; c < 6; ++c) a2l[lane * 6 + c] = e[c] * inv;
    }
    __syncthreads();
#pragma unroll
    for (int i = 0; i < 8; ++i) {
        float acc = 0.f;
#pragma unroll
        for (int c = 0; c < 6; ++c)
            acc += a2l[i * 6 + c] * bf2f(qbf[(long)(bt * C_ + c) * 512 + i * 64 + lane]);
        x[(long)bt * 512 + i * 64 + lane] = acc;
    }
}

// ---------------------------------------------------------------------------
extern "C" void kernel_launch(void* const* d_in, const int* in_sizes, int n_in,
                              void* d_out, int out_size, void* d_ws, size_t ws_size,
                              hipStream_t stream) {
    const float* query = (const float*)d_in[0];
    const float* key   = (const float*)d_in[1];
    const float* value = (const float*)d_in[2];
    const int*   mask  = (const int*)d_in[3];
    const float* Wq = (const float*)d_in[4];
    const float* bq = (const float*)d_in[5];
    const float* Wk = (const float*)d_in[6];
    const float* bk = (const float*)d_in[7];
    const float* Wv = (const float*)d_in[8];
    const float* bv = (const float*)d_in[9];
    const float* Wo = (const float*)d_in[10];
    const float* bo = (const float*)d_in[11];
    float* out = (float*)d_out;

    char* ws = (char*)d_ws;
    ushort* Wqbf = (ushort*)(ws + 0);                 // 512 KB bf16
    float* WkT = (float*)(ws + (1u << 20));
    float* WvT = (float*)(ws + (2u << 20));
    float* WoT = (float*)(ws + (3u << 20));
    float* kproj = (float*)(ws + (4u << 20));
    float* vproj = (float*)(ws + (4u << 20) + 262144u);
    __hip_bfloat16* qbf = (__hip_bfloat16*)(ws + 4718592u);
    float* q1 = (float*)(ws + 55050240u);
    float* pc = (float*)(ws + 71827456u);
    float* x  = (float*)(ws + 88604672u);

    dim3 tb(32, 8), tg(16, 16);
    convert_bf16_512<<<256, 256, 0, stream>>>(Wq, Wqbf);
    transpose512<<<tg, tb, 0, stream>>>(Wk, WkT);
    transpose512<<<tg, tb, 0, stream>>>(Wv, WvT);
    transpose512<<<tg, tb, 0, stream>>>(Wo, WoT);

    kv_proj<<<B_ * S_, 512, 0, stream>>>(key, value, WkT, WvT, bk, bv, kproj, vproj);

    // Q projection: M = B*T*C = 49152 rows (ordered (b,t,c)), bf16 out, MFMA
    qproj_mfma<<<1536, 256, 0, stream>>>(query, Wqbf, bq, (ushort*)qbf);

    q1_mean<<<16384, 256, 0, stream>>>(qbf, q1);

    stage1<<<B_ * T_, 64, 0, stream>>>(q1, kproj, vproj, mask, pc);
    stage2<<<B_ * T_, 64, 0, stream>>>(pc, qbf, x);

    // output projection: M = B*T = 8192, fp32 out (kept fp32 for accuracy headroom)
    gemm_tn<0, 0><<<dim3(64, 4), 256, 0, stream>>>(x, WoT, bo, out, 8192);

    (void)in_sizes; (void)n_in; (void)out_size; (void)ws_size;
}

// Round 3
// 167.527 us; speedup vs baseline: 2.9759x; 1.6717x over previous
//
#include <hip/hip_runtime.h>
#include <hip/hip_bf16.h>

// Problem constants
#define B_  16
#define C_  6
#define T_  512
#define S_  8

typedef __attribute__((ext_vector_type(8))) short bf16x8;
typedef __attribute__((ext_vector_type(4))) float f32x4;

__device__ __forceinline__ ushort f2bf(float f) {
    __hip_bfloat16 h = __float2bfloat16(f);
    return *reinterpret_cast<ushort*>(&h);
}
__device__ __forceinline__ float bf2f(__hip_bfloat16 h) {
    return __bfloat162float(h);
}
__device__ __forceinline__ float bfu2f(ushort u) {
    uint x = (uint)u << 16;
    union { uint u; float f; } c; c.u = x; return c.f;
}

// ---------------------------------------------------------------------------
// 512x512 transpose (for kv_proj coalesced B-reads)
__global__ void transpose512(const float* __restrict__ src, float* __restrict__ dst) {
    __shared__ float tile[32][33];
    int bx = blockIdx.x * 32, by = blockIdx.y * 32;
    int tx = threadIdx.x, ty = threadIdx.y;
    for (int i = 0; i < 32; i += 8)
        tile[ty + i][tx] = src[(long)(by + ty + i) * 512 + bx + tx];
    __syncthreads();
    for (int i = 0; i < 32; i += 8)
        dst[(long)(bx + ty + i) * 512 + by + tx] = tile[tx][ty + i];
}

// fp32 -> bf16 elementwise (512x512 weights)
__global__ void convert_bf16_512(const float* __restrict__ src, ushort* __restrict__ dst) {
    int i = (blockIdx.x * 256 + threadIdx.x) * 4;
    float4 v = *(const float4*)(src + i);
    ushort4 o;
    o.x = f2bf(v.x); o.y = f2bf(v.y); o.z = f2bf(v.z); o.w = f2bf(v.w);
    *(ushort4*)(dst + i) = o;
}

// ---------------------------------------------------------------------------
// K/V projections (tiny: 128 rows)
__global__ void kv_proj(const float* __restrict__ key, const float* __restrict__ value,
                        const float* __restrict__ WkT, const float* __restrict__ WvT,
                        const float* __restrict__ bk, const float* __restrict__ bv,
                        float* __restrict__ kout, float* __restrict__ vout) {
    int row = blockIdx.x;      // b*S + s
    int j = threadIdx.x;       // 0..511
    __shared__ float krow[512];
    __shared__ float vrow[512];
    krow[j] = key[(long)row * 512 + j];
    vrow[j] = value[(long)row * 512 + j];
    __syncthreads();
    float ak = bk[j], av = bv[j];
    for (int f = 0; f < 512; ++f) {
        ak += krow[f] * WkT[(long)f * 512 + j];
        av += vrow[f] * WvT[(long)f * 512 + j];
    }
    kout[(long)row * 512 + j] = ak;
    vout[(long)row * 512 + j] = av;
}

// ---------------------------------------------------------------------------
// MFMA bf16 GEMM, double-buffered LDS, raw-barrier 2-phase pipeline.
// out[m,n] = sum_k A[m,k]*W[n,k] + bias[n]; N=K=512.
// 128x128 tile, BK=64, 4 waves (2x2), 64x64/wave, grid = mpanels*4 (%8==0).
// PERM: A row m=((b*T+t)*C+c) maps to query row (b,c,t) (fp32 A only).
// ABF16: A is bf16 (no conversion); else fp32 (cvt in staging).
// OUTBF: bf16 output, else fp32.
template <int PERM, int ABF16, int OUTBF>
__global__ __launch_bounds__(256) void gemm_mfma(const void* __restrict__ Ain,
                                                 const ushort* __restrict__ Wbf,
                                                 const float* __restrict__ bias,
                                                 void* __restrict__ out, int mpanels) {
    __shared__ ushort lds[32768];   // 64 KB: buf b at b*16384 (As 8192, Ws 8192)

    const int bid = blockIdx.x;
    const int cpx = (mpanels * 4) >> 3;
    const int swz = (bid & 7) * cpx + (bid >> 3);   // XCD-bijective (grid%8==0)
    const int bm = (swz >> 2) * 128;
    const int bn = (swz & 3) * 128;

    const int tid  = threadIdx.x;
    const int lane = tid & 63;
    const int wv   = tid >> 6;
    const int wm   = (wv >> 1) * 64;
    const int wn   = (wv & 1) * 64;
    const int ln15 = lane & 15;
    const int ln16 = lane >> 4;

    // staging slots: thread -> (rows r0+32i, 8-elem k-chunk kc)
    const int kc = tid & 7;
    const int r0 = tid >> 3;

    long asrc[4];
#pragma unroll
    for (int i = 0; i < 4; ++i) {
        int m = bm + r0 + 32 * i;
        if (PERM) {
            int c  = m % 6;
            int bt = m / 6;
            int b  = bt >> 9;
            int t  = bt & 511;
            asrc[i] = ((long)(b * 6 + c) * 512 + t) * 512;
        } else {
            asrc[i] = (long)m * 512;
        }
    }
    const ushort* wsrc = Wbf + (long)(bn + r0) * 512 + kc * 8;

    float4 ra[4][2];   // fp32 A staging
    uint4  rab[4];     // bf16 A staging
    uint4  rw[4];      // W staging

    auto LOAD = [&](int k0) {
#pragma unroll
        for (int i = 0; i < 4; ++i) {
            if (ABF16) {
                rab[i] = *(const uint4*)((const ushort*)Ain + asrc[i] + k0 + kc * 8);
            } else {
                const float* ap = (const float*)Ain + asrc[i] + k0 + kc * 8;
                ra[i][0] = *(const float4*)ap;
                ra[i][1] = *(const float4*)(ap + 4);
            }
            rw[i] = *(const uint4*)(wsrc + (long)(32 * i) * 512 + k0);
        }
    };
    auto WRITE = [&](ushort* As, ushort* Ws) {
#pragma unroll
        for (int i = 0; i < 4; ++i) {
            int r = r0 + 32 * i;
            int idx = r * 64 + ((kc ^ (r & 7)) << 3);
            if (ABF16) {
                *(uint4*)&As[idx] = rab[i];
            } else {
                uint4 pk;
                pk.x = (uint)f2bf(ra[i][0].x) | ((uint)f2bf(ra[i][0].y) << 16);
                pk.y = (uint)f2bf(ra[i][0].z) | ((uint)f2bf(ra[i][0].w) << 16);
                pk.z = (uint)f2bf(ra[i][1].x) | ((uint)f2bf(ra[i][1].y) << 16);
                pk.w = (uint)f2bf(ra[i][1].z) | ((uint)f2bf(ra[i][1].w) << 16);
                *(uint4*)&As[idx] = pk;
            }
            *(uint4*)&Ws[idx] = rw[i];
        }
    };

    f32x4 acc[4][4] = {};

    // prologue: tile 0 into buf 0
    LOAD(0);
    WRITE(lds, lds + 8192);
    asm volatile("s_waitcnt lgkmcnt(0)" ::: "memory");
    __builtin_amdgcn_s_barrier();
    asm volatile("" ::: "memory");

    int cur = 0;
    for (int kt = 0; kt < 8; ++kt) {
        if (kt < 7) LOAD((kt + 1) * 64);     // loads stay in flight across barrier
        ushort* As = lds + cur * 16384;
        ushort* Ws = As + 8192;
#pragma unroll
        for (int kj = 0; kj < 2; ++kj) {
            bf16x8 af[4], bfv[4];
#pragma unroll
            for (int mi = 0; mi < 4; ++mi) {
                int row = wm + mi * 16 + ln15;
                int ch  = kj * 4 + ln16;
                af[mi] = *(const bf16x8*)&As[row * 64 + ((ch ^ (row & 7)) << 3)];
            }
#pragma unroll
            for (int ni = 0; ni < 4; ++ni) {
                int row = wn + ni * 16 + ln15;
                int ch  = kj * 4 + ln16;
                bfv[ni] = *(const bf16x8*)&Ws[row * 64 + ((ch ^ (row & 7)) << 3)];
            }
#pragma unroll
            for (int mi = 0; mi < 4; ++mi)
#pragma unroll
                for (int ni = 0; ni < 4; ++ni)
                    acc[mi][ni] = __builtin_amdgcn_mfma_f32_16x16x32_bf16(
                        af[mi], bfv[ni], acc[mi][ni], 0, 0, 0);
        }
        if (kt < 7) {
            ushort* nAs = lds + (cur ^ 1) * 16384;
            WRITE(nAs, nAs + 8192);          // compiler inserts vmcnt for reg deps
            asm volatile("s_waitcnt lgkmcnt(0)" ::: "memory");
            __builtin_amdgcn_s_barrier();
            asm volatile("" ::: "memory");
            cur ^= 1;
        }
    }

    // ---- epilogue: LDS-staged coalesced stores ----
    asm volatile("s_waitcnt lgkmcnt(0)" ::: "memory");
    __builtin_amdgcn_s_barrier();
    asm volatile("" ::: "memory");

    float bsv[4];
#pragma unroll
    for (int ni = 0; ni < 4; ++ni)
        bsv[ni] = bias[bn + wn + ni * 16 + ln15];

    if (OUTBF) {
        ushort* eb = lds;    // 128x128 bf16 = 32 KB
#pragma unroll
        for (int mi = 0; mi < 4; ++mi)
#pragma unroll
            for (int j = 0; j < 4; ++j) {
                int row = wm + mi * 16 + ln16 * 4 + j;
#pragma unroll
                for (int ni = 0; ni < 4; ++ni) {
                    int col = wn + ni * 16 + ln15;
                    int cs  = col ^ ((row & 12) << 2);
                    eb[row * 128 + cs] = f2bf(acc[mi][ni][j] + bsv[ni]);
                }
            }
        asm volatile("s_waitcnt lgkmcnt(0)" ::: "memory");
        __builtin_amdgcn_s_barrier();
        asm volatile("" ::: "memory");
#pragma unroll
        for (int i = 0; i < 8; ++i) {
            int idx = i * 2048 + tid * 8;
            int row = idx >> 7, col = idx & 127;
            int cs  = col ^ ((row & 12) << 2);
            uint4 v = *(const uint4*)&eb[row * 128 + cs];
            *(uint4*)((ushort*)out + (long)(bm + row) * 512 + bn + col) = v;
        }
    } else {
        float* ef = (float*)lds;   // 128x128 fp32 = 64 KB
#pragma unroll
        for (int mi = 0; mi < 4; ++mi)
#pragma unroll
            for (int j = 0; j < 4; ++j) {
                int row = wm + mi * 16 + ln16 * 4 + j;
#pragma unroll
                for (int ni = 0; ni < 4; ++ni) {
                    int col = wn + ni * 16 + ln15;
                    int cs  = col ^ ((row & 12) << 2);
                    ef[row * 128 + cs] = acc[mi][ni][j] + bsv[ni];
                }
            }
        asm volatile("s_waitcnt lgkmcnt(0)" ::: "memory");
        __builtin_amdgcn_s_barrier();
        asm volatile("" ::: "memory");
#pragma unroll
        for (int i = 0; i < 16; ++i) {
            int idx = i * 1024 + tid * 4;
            int row = idx >> 7, col = idx & 127;
            int cs  = col ^ ((row & 12) << 2);
            float4 v = *(const float4*)&ef[row * 128 + cs];
            *(float4*)((float*)out + (long)(bm + row) * 512 + bn + col) = v;
        }
    }
}

// ---------------------------------------------------------------------------
// Fused q1_mean + stage1 + stage2. One wave per (b,t). x out in bf16.
__global__ __launch_bounds__(64) void fused_attn(const ushort* __restrict__ qbf,
                                                 const float* __restrict__ kproj,
                                                 const float* __restrict__ vproj,
                                                 const int* __restrict__ mask,
                                                 ushort* __restrict__ xout) {
    int bt = blockIdx.x;
    int b = bt >> 9, t = bt & 511;
    int lane = threadIdx.x;

    __shared__ ushort qlds[6 * 512];   // 6 KB
    __shared__ float q1l[512];
    __shared__ float pcl[512];
    __shared__ float ssl[48];
    __shared__ float a2l[48];

    // load the 6 q-rows (b,t,c=0..5), coalesced uint4
    const ushort* qsrc = qbf + (long)bt * (6 * 512);
#pragma unroll
    for (int i = 0; i < 6; ++i) {
        int idx = (i * 64 + lane) * 8;
        *(uint4*)&qlds[idx] = *(const uint4*)(qsrc + idx);
    }
    __syncthreads();

    // q1 = mean over c (each lane owns 8 consecutive f)
    {
        float s[8] = {};
#pragma unroll
        for (int c = 0; c < 6; ++c) {
            const ushort* qr = &qlds[c * 512 + lane * 8];
#pragma unroll
            for (int j = 0; j < 8; ++j) s[j] += bfu2f(qr[j]);
        }
#pragma unroll
        for (int j = 0; j < 8; ++j) q1l[lane * 8 + j] = s[j] * (1.0f / 6.0f);
    }
    __syncthreads();

    // stage 1: lane = (h, s)
    int h = lane >> 3, s = lane & 7;
    const float* krow = kproj + (long)(b * S_ + s) * 512 + h * 64;
    float sc = 0.f;
#pragma unroll
    for (int d = 0; d < 64; d += 4) {
        float4 kv = *(const float4*)(krow + d);
        sc += q1l[h * 64 + d]     * kv.x;
        sc += q1l[h * 64 + d + 1] * kv.y;
        sc += q1l[h * 64 + d + 2] * kv.z;
        sc += q1l[h * 64 + d + 3] * kv.w;
    }
    sc *= 0.125f;   // 1/sqrt(64)
    int mk = mask[((long)b * T_ + t) * S_ + s];
    if (mk == 0) sc = -1e30f;
    float mx = sc;
    for (int off = 1; off < 8; off <<= 1) mx = fmaxf(mx, __shfl_xor(mx, off));
    float e = __expf(sc - mx);
    float sum = e;
    for (int off = 1; off < 8; off <<= 1) sum += __shfl_xor(sum, off);
    float attn = e / sum;
    if (mk == 0) attn = 0.f;

    // pc[h=i] = sum_s attn * v
#pragma unroll
    for (int i = 0; i < 8; ++i) {
        float acc = 0.f;
#pragma unroll
        for (int s2 = 0; s2 < 8; ++s2) {
            float a = __shfl(attn, i * 8 + s2);
            acc += a * vproj[(long)(b * S_ + s2) * 512 + i * 64 + lane];
        }
        pcl[i * 64 + lane] = acc;
    }
    __syncthreads();

    // stage 2: ss[h,c], softmax over c
    if (lane < 48) {
        int hh = lane / 6, cc = lane % 6;
        const float* pr = &pcl[hh * 64];
        const ushort* qr = &qlds[cc * 512 + hh * 64];
        float acc = 0.f;
#pragma unroll 8
        for (int d = 0; d < 64; ++d) acc += pr[d] * bfu2f(qr[d]);
        ssl[lane] = acc * 0.125f;
    }
    __syncthreads();
    if (lane < 8) {
        float mx2 = -1e30f;
#pragma unroll
        for (int c = 0; c < 6; ++c) mx2 = fmaxf(mx2, ssl[lane * 6 + c]);
        float ex[6];
        float sm = 0.f;
#pragma unroll
        for (int c = 0; c < 6; ++c) {
            ex[c] = __expf(ssl[lane * 6 + c] - mx2);
            sm += ex[c];
        }
        float inv = 1.0f / sm;
#pragma unroll
        for (int c = 0; c < 6; ++c) a2l[lane * 6 + c] = ex[c] * inv;
    }
    __syncthreads();

    // x = attn2-weighted sum of q_c, bf16 out
#pragma unroll
    for (int i = 0; i < 8; ++i) {
        float acc = 0.f;
#pragma unroll
        for (int c = 0; c < 6; ++c)
            acc += a2l[i * 6 + c] * bfu2f(qlds[c * 512 + i * 64 + lane]);
        xout[(long)bt * 512 + i * 64 + lane] = f2bf(acc);
    }
}

// ---------------------------------------------------------------------------
extern "C" void kernel_launch(void* const* d_in, const int* in_sizes, int n_in,
                              void* d_out, int out_size, void* d_ws, size_t ws_size,
                              hipStream_t stream) {
    const float* query = (const float*)d_in[0];
    const float* key   = (const float*)d_in[1];
    const float* value = (const float*)d_in[2];
    const int*   mask  = (const int*)d_in[3];
    const float* Wq = (const float*)d_in[4];
    const float* bq = (const float*)d_in[5];
    const float* Wk = (const float*)d_in[6];
    const float* bk = (const float*)d_in[7];
    const float* Wv = (const float*)d_in[8];
    const float* bv = (const float*)d_in[9];
    const float* Wo = (const float*)d_in[10];
    const float* bo = (const float*)d_in[11];
    float* out = (float*)d_out;

    char* ws = (char*)d_ws;
    ushort* Wqbf  = (ushort*)(ws + 0);                  // 512 KB
    ushort* Wobf  = (ushort*)(ws + 524288u);            // 512 KB
    float*  WkT   = (float*)(ws + (1u << 20));          // 1 MB
    float*  WvT   = (float*)(ws + (2u << 20));          // 1 MB
    float*  kproj = (float*)(ws + (3u << 20));          // 256 KB
    float*  vproj = (float*)(ws + (3u << 20) + 262144u);
    ushort* qbf   = (ushort*)(ws + (4u << 20));         // 48 MB (49152 x 512 bf16)
    ushort* xbf   = (ushort*)(ws + 54525952u);          // 8 MB (8192 x 512 bf16)

    dim3 tb(32, 8), tg(16, 16);
    convert_bf16_512<<<256, 256, 0, stream>>>(Wq, Wqbf);
    convert_bf16_512<<<256, 256, 0, stream>>>(Wo, Wobf);
    transpose512<<<tg, tb, 0, stream>>>(Wk, WkT);
    transpose512<<<tg, tb, 0, stream>>>(Wv, WvT);

    kv_proj<<<B_ * S_, 512, 0, stream>>>(key, value, WkT, WvT, bk, bv, kproj, vproj);

    // Q projection: M = 49152 rows (b,t,c), fp32 A with PERM, bf16 out
    gemm_mfma<1, 0, 1><<<1536, 256, 0, stream>>>(query, Wqbf, bq, qbf, 384);

    // fused q1_mean + stage1 + stage2 -> x (bf16)
    fused_attn<<<B_ * T_, 64, 0, stream>>>(qbf, kproj, vproj, mask, xbf);

    // output projection: M = 8192, bf16 A, fp32 out
    gemm_mfma<0, 1, 0><<<256, 256, 0, stream>>>(xbf, Wobf, bo, out, 64);

    (void)in_sizes; (void)n_in; (void)out_size; (void)ws_size;
}

// Round 4
// 123.407 us; speedup vs baseline: 4.0398x; 1.3575x over previous
//
#include <hip/hip_runtime.h>
#include <hip/hip_bf16.h>

// Problem constants
#define B_  16
#define C_  6
#define T_  512
#define S_  8

#define AS1 __attribute__((address_space(1)))
#define AS3 __attribute__((address_space(3)))

typedef __attribute__((ext_vector_type(8))) short bf16x8;
typedef __attribute__((ext_vector_type(4))) float f32x4;

__device__ __forceinline__ ushort f2bf(float f) {
    __hip_bfloat16 h = __float2bfloat16(f);
    return *reinterpret_cast<ushort*>(&h);
}
__device__ __forceinline__ float bfu2f(ushort u) {
    uint x = (uint)u << 16;
    union { uint u; float f; } c; c.u = x; return c.f;
}

// ---------------------------------------------------------------------------
// Two 512x512 transposes in one launch (Wk->WkT, Wv->WvT)
__global__ void transpose2(const float* __restrict__ s0, const float* __restrict__ s1,
                           float* __restrict__ d0, float* __restrict__ d1) {
    const float* src = blockIdx.z ? s1 : s0;
    float* dst = blockIdx.z ? d1 : d0;
    __shared__ float tile[32][33];
    int bx = blockIdx.x * 32, by = blockIdx.y * 32;
    int tx = threadIdx.x, ty = threadIdx.y;
    for (int i = 0; i < 32; i += 8)
        tile[ty + i][tx] = src[(long)(by + ty + i) * 512 + bx + tx];
    __syncthreads();
    for (int i = 0; i < 32; i += 8)
        dst[(long)(bx + ty + i) * 512 + by + tx] = tile[tx][ty + i];
}

// Two fp32->bf16 512x512 conversions in one launch (Wq, Wo)
__global__ void convert2(const float* __restrict__ s0, const float* __restrict__ s1,
                         ushort* __restrict__ d0, ushort* __restrict__ d1) {
    const float* s = blockIdx.y ? s1 : s0;
    ushort* d = blockIdx.y ? d1 : d0;
    int i = (blockIdx.x * 256 + threadIdx.x) * 4;
    float4 v = *(const float4*)(s + i);
    ushort4 o;
    o.x = f2bf(v.x); o.y = f2bf(v.y); o.z = f2bf(v.z); o.w = f2bf(v.w);
    *(ushort4*)(d + i) = o;
}

// ---------------------------------------------------------------------------
// K/V projections (tiny: 128 rows)
__global__ void kv_proj(const float* __restrict__ key, const float* __restrict__ value,
                        const float* __restrict__ WkT, const float* __restrict__ WvT,
                        const float* __restrict__ bk, const float* __restrict__ bv,
                        float* __restrict__ kout, float* __restrict__ vout) {
    int row = blockIdx.x;      // b*S + s
    int j = threadIdx.x;       // 0..511
    __shared__ float krow[512];
    __shared__ float vrow[512];
    krow[j] = key[(long)row * 512 + j];
    vrow[j] = value[(long)row * 512 + j];
    __syncthreads();
    float ak = bk[j], av = bv[j];
    for (int f = 0; f < 512; ++f) {
        ak += krow[f] * WkT[(long)f * 512 + j];
        av += vrow[f] * WvT[(long)f * 512 + j];
    }
    kout[(long)row * 512 + j] = ak;
    vout[(long)row * 512 + j] = av;
}

// ---------------------------------------------------------------------------
// MFMA bf16 GEMM, m97 structure: single 32KB LDS buffer, 2 raw barriers/K-step,
// W (and A when bf16) staged via global_load_lds w=16 with pre-swizzled source
// (linear LDS dest + inverse-swizzled per-lane global addr + swizzled read).
// fp32 A reg-staged (loads issued during MFMA phase, cvt+ds_write after bar1).
// out[m,n] = sum_k A[m,k]*W[n,k] + bias[n]; N=K=512.
// 128x128 tile, BK=64, 4 waves (2x2), 64x64/wave, grid = mpanels*4 (%8==0).
template <int PERM, int ABF16, int OUTBF>
__global__ __launch_bounds__(256, 3) void gemm_mfma(const void* __restrict__ Ain,
                                                    const ushort* __restrict__ Wbf,
                                                    const float* __restrict__ bias,
                                                    void* __restrict__ out, int mpanels) {
    __shared__ __align__(16) ushort lds[16384];   // 32 KB: As[0..8191], Ws[8192..]
    ushort* Asb = lds;
    ushort* Wsb = lds + 8192;

    const int bid = blockIdx.x;
    const int cpx = (mpanels * 4) >> 3;
    const int swz = (bid & 7) * cpx + (bid >> 3);   // XCD-bijective (grid%8==0)
    const int bm = (swz >> 2) * 128;
    const int bn = (swz & 3) * 128;

    const int tid  = threadIdx.x;
    const int lane = tid & 63;
    const int wv   = tid >> 6;
    const int wm   = (wv >> 1) * 64;
    const int wn   = (wv & 1) * 64;
    const int ln15 = lane & 15;
    const int ln16 = lane >> 4;

    // fp32-A staging slots: thread -> (rows r0+32i, 8-elem k-chunk kc)
    const int kc = tid & 7;
    const int r0 = tid >> 3;

    long asrc[4];
    if (!ABF16) {
#pragma unroll
        for (int i = 0; i < 4; ++i) {
            int m = bm + r0 + 32 * i;
            if (PERM) {
                int c  = m % 6;
                int bt = m / 6;
                int b  = bt >> 9;
                int t  = bt & 511;
                asrc[i] = ((long)(b * 6 + c) * 512 + t) * 512;
            } else {
                asrc[i] = (long)m * 512;
            }
        }
    }

    float4 ra[4][2];

    auto LOADA = [&](int k0) {
#pragma unroll
        for (int i = 0; i < 4; ++i) {
            const float* ap = (const float*)Ain + asrc[i] + k0 + kc * 8;
            ra[i][0] = *(const float4*)ap;
            ra[i][1] = *(const float4*)(ap + 4);
        }
    };
    auto WRITEA = [&]() {
#pragma unroll
        for (int i = 0; i < 4; ++i) {
            int r = r0 + 32 * i;
            int idx = r * 64 + ((kc ^ (r & 7)) << 3);
            uint4 pk;
            pk.x = (uint)f2bf(ra[i][0].x) | ((uint)f2bf(ra[i][0].y) << 16);
            pk.y = (uint)f2bf(ra[i][0].z) | ((uint)f2bf(ra[i][0].w) << 16);
            pk.z = (uint)f2bf(ra[i][1].x) | ((uint)f2bf(ra[i][1].y) << 16);
            pk.w = (uint)f2bf(ra[i][1].z) | ((uint)f2bf(ra[i][1].w) << 16);
            *(uint4*)&Asb[idx] = pk;
        }
    };
    // global_load_lds stage of a 128x64 bf16 tile: wave wv covers rows wv*32..+31.
    // LDS dest linear (base + lane*16B); source pre-swizzled so the swizzled
    // fragment read (chunk ^= row&7) sees W[row][k0 + ch*8].
    auto GLDS = [&](const ushort* gbase, int rowbase, ushort* ldsbase, int k0) {
        int rb = wv * 32 + (lane >> 3);
        int c  = lane & 7;
#pragma unroll
        for (int i = 0; i < 4; ++i) {
            int r = rb + i * 8;
            const ushort* src = gbase + (long)(rowbase + r) * 512 + k0 + ((c ^ (r & 7)) << 3);
            ushort* dst = ldsbase + wv * 2048 + i * 512;   // wave-uniform base
            __builtin_amdgcn_global_load_lds((AS1 const void*)src, (AS3 void*)dst, 16, 0, 0);
        }
    };

    f32x4 acc[4][4] = {};

    // ---- prologue: stage tile 0 ----
    if (ABF16) {
        GLDS((const ushort*)Ain, bm, Asb, 0);
    } else {
        LOADA(0);
        WRITEA();
    }
    GLDS(Wbf, bn, Wsb, 0);
    asm volatile("s_waitcnt vmcnt(0) lgkmcnt(0)" ::: "memory");
    __builtin_amdgcn_s_barrier();
    asm volatile("" ::: "memory");

    for (int kt = 0; kt < 8; ++kt) {
        if (!ABF16 && kt < 7) LOADA((kt + 1) * 64);   // in flight across MFMA phase
#pragma unroll
        for (int kj = 0; kj < 2; ++kj) {
            bf16x8 af[4], bfv[4];
#pragma unroll
            for (int mi = 0; mi < 4; ++mi) {
                int row = wm + mi * 16 + ln15;
                int ch  = kj * 4 + ln16;
                af[mi] = *(const bf16x8*)&Asb[row * 64 + ((ch ^ (row & 7)) << 3)];
            }
#pragma unroll
            for (int ni = 0; ni < 4; ++ni) {
                int row = wn + ni * 16 + ln15;
                int ch  = kj * 4 + ln16;
                bfv[ni] = *(const bf16x8*)&Wsb[row * 64 + ((ch ^ (row & 7)) << 3)];
            }
#pragma unroll
            for (int mi = 0; mi < 4; ++mi)
#pragma unroll
                for (int ni = 0; ni < 4; ++ni)
                    acc[mi][ni] = __builtin_amdgcn_mfma_f32_16x16x32_bf16(
                        af[mi], bfv[ni], acc[mi][ni], 0, 0, 0);
        }
        // barrier1: all waves done reading this tile (no vmcnt drain - A loads fly)
        asm volatile("" ::: "memory");
        __builtin_amdgcn_s_barrier();
        asm volatile("" ::: "memory");
        if (kt < 7) {
            if (ABF16) GLDS((const ushort*)Ain, bm, Asb, (kt + 1) * 64);
            else       WRITEA();
            GLDS(Wbf, bn, Wsb, (kt + 1) * 64);
            asm volatile("s_waitcnt vmcnt(0) lgkmcnt(0)" ::: "memory");
            __builtin_amdgcn_s_barrier();
            asm volatile("" ::: "memory");
        }
    }

    // ---- epilogue (LDS free after final barrier1) ----
    float bsv[4];
#pragma unroll
    for (int ni = 0; ni < 4; ++ni)
        bsv[ni] = bias[bn + wn + ni * 16 + ln15];

    if (OUTBF) {
        ushort* eb = lds;    // 128x128 bf16 = 32 KB (exact fit)
#pragma unroll
        for (int mi = 0; mi < 4; ++mi)
#pragma unroll
            for (int j = 0; j < 4; ++j) {
                int row = wm + mi * 16 + ln16 * 4 + j;
#pragma unroll
                for (int ni = 0; ni < 4; ++ni) {
                    int col = wn + ni * 16 + ln15;
                    int cs  = col ^ ((row & 12) << 2);
                    eb[row * 128 + cs] = f2bf(acc[mi][ni][j] + bsv[ni]);
                }
            }
        asm volatile("s_waitcnt lgkmcnt(0)" ::: "memory");
        __builtin_amdgcn_s_barrier();
        asm volatile("" ::: "memory");
#pragma unroll
        for (int i = 0; i < 8; ++i) {
            int idx = i * 2048 + tid * 8;
            int row = idx >> 7, col = idx & 127;
            int cs  = col ^ ((row & 12) << 2);
            uint4 v = *(const uint4*)&eb[row * 128 + cs];
            *(uint4*)((ushort*)out + (long)(bm + row) * 512 + bn + col) = v;
        }
    } else {
        // fp32 out: stage in two 64-row halves (32 KB each)
        float* ef = (float*)lds;
#pragma unroll
        for (int half = 0; half < 2; ++half) {
            if (wm == half * 64) {
#pragma unroll
                for (int mi = 0; mi < 4; ++mi)
#pragma unroll
                    for (int j = 0; j < 4; ++j) {
                        int lr = mi * 16 + ln16 * 4 + j;
#pragma unroll
                        for (int ni = 0; ni < 4; ++ni) {
                            int col = wn + ni * 16 + ln15;
                            int cs  = col ^ ((lr & 12) << 2);
                            ef[lr * 128 + cs] = acc[mi][ni][j] + bsv[ni];
                        }
                    }
            }
            asm volatile("s_waitcnt lgkmcnt(0)" ::: "memory");
            __builtin_amdgcn_s_barrier();
            asm volatile("" ::: "memory");
#pragma unroll
            for (int i = 0; i < 8; ++i) {
                int idx = i * 1024 + tid * 4;
                int lr = idx >> 7, col = idx & 127;
                int cs = col ^ ((lr & 12) << 2);
                float4 v = *(const float4*)&ef[lr * 128 + cs];
                *(float4*)((float*)out + (long)(bm + half * 64 + lr) * 512 + bn + col) = v;
            }
            if (half == 0) {
                asm volatile("" ::: "memory");
                __builtin_amdgcn_s_barrier();
                asm volatile("" ::: "memory");
            }
        }
    }
}

// ---------------------------------------------------------------------------
// Fused q1_mean + stage1 + stage2. One wave per (b,t). x out in bf16.
__global__ __launch_bounds__(64) void fused_attn(const ushort* __restrict__ qbf,
                                                 const float* __restrict__ kproj,
                                                 const float* __restrict__ vproj,
                                                 const int* __restrict__ mask,
                                                 ushort* __restrict__ xout) {
    int bt = blockIdx.x;
    int b = bt >> 9, t = bt & 511;
    int lane = threadIdx.x;

    __shared__ ushort qlds[6 * 512];
    __shared__ float q1l[512];
    __shared__ float pcl[512];
    __shared__ float ssl[48];
    __shared__ float a2l[48];

    const ushort* qsrc = qbf + (long)bt * (6 * 512);
#pragma unroll
    for (int i = 0; i < 6; ++i) {
        int idx = (i * 64 + lane) * 8;
        *(uint4*)&qlds[idx] = *(const uint4*)(qsrc + idx);
    }
    __syncthreads();

    {
        float s[8] = {};
#pragma unroll
        for (int c = 0; c < 6; ++c) {
            const ushort* qr = &qlds[c * 512 + lane * 8];
#pragma unroll
            for (int j = 0; j < 8; ++j) s[j] += bfu2f(qr[j]);
        }
#pragma unroll
        for (int j = 0; j < 8; ++j) q1l[lane * 8 + j] = s[j] * (1.0f / 6.0f);
    }
    __syncthreads();

    int h = lane >> 3, s = lane & 7;
    const float* krow = kproj + (long)(b * S_ + s) * 512 + h * 64;
    float sc = 0.f;
#pragma unroll
    for (int d = 0; d < 64; d += 4) {
        float4 kv = *(const float4*)(krow + d);
        sc += q1l[h * 64 + d]     * kv.x;
        sc += q1l[h * 64 + d + 1] * kv.y;
        sc += q1l[h * 64 + d + 2] * kv.z;
        sc += q1l[h * 64 + d + 3] * kv.w;
    }
    sc *= 0.125f;
    int mk = mask[((long)b * T_ + t) * S_ + s];
    if (mk == 0) sc = -1e30f;
    float mx = sc;
    for (int off = 1; off < 8; off <<= 1) mx = fmaxf(mx, __shfl_xor(mx, off));
    float e = __expf(sc - mx);
    float sum = e;
    for (int off = 1; off < 8; off <<= 1) sum += __shfl_xor(sum, off);
    float attn = e / sum;
    if (mk == 0) attn = 0.f;

#pragma unroll
    for (int i = 0; i < 8; ++i) {
        float acc = 0.f;
#pragma unroll
        for (int s2 = 0; s2 < 8; ++s2) {
            float a = __shfl(attn, i * 8 + s2);
            acc += a * vproj[(long)(b * S_ + s2) * 512 + i * 64 + lane];
        }
        pcl[i * 64 + lane] = acc;
    }
    __syncthreads();

    if (lane < 48) {
        int hh = lane / 6, cc = lane % 6;
        const float* pr = &pcl[hh * 64];
        const ushort* qr = &qlds[cc * 512 + hh * 64];
        float acc = 0.f;
#pragma unroll 8
        for (int d = 0; d < 64; ++d) acc += pr[d] * bfu2f(qr[d]);
        ssl[lane] = acc * 0.125f;
    }
    __syncthreads();
    if (lane < 8) {
        float mx2 = -1e30f;
#pragma unroll
        for (int c = 0; c < 6; ++c) mx2 = fmaxf(mx2, ssl[lane * 6 + c]);
        float ex[6];
        float sm = 0.f;
#pragma unroll
        for (int c = 0; c < 6; ++c) {
            ex[c] = __expf(ssl[lane * 6 + c] - mx2);
            sm += ex[c];
        }
        float inv = 1.0f / sm;
#pragma unroll
        for (int c = 0; c < 6; ++c) a2l[lane * 6 + c] = ex[c] * inv;
    }
    __syncthreads();

#pragma unroll
    for (int i = 0; i < 8; ++i) {
        float acc = 0.f;
#pragma unroll
        for (int c = 0; c < 6; ++c)
            acc += a2l[i * 6 + c] * bfu2f(qlds[c * 512 + i * 64 + lane]);
        xout[(long)bt * 512 + i * 64 + lane] = f2bf(acc);
    }
}

// ---------------------------------------------------------------------------
extern "C" void kernel_launch(void* const* d_in, const int* in_sizes, int n_in,
                              void* d_out, int out_size, void* d_ws, size_t ws_size,
                              hipStream_t stream) {
    const float* query = (const float*)d_in[0];
    const float* key   = (const float*)d_in[1];
    const float* value = (const float*)d_in[2];
    const int*   mask  = (const int*)d_in[3];
    const float* Wq = (const float*)d_in[4];
    const float* bq = (const float*)d_in[5];
    const float* Wk = (const float*)d_in[6];
    const float* bk = (const float*)d_in[7];
    const float* Wv = (const float*)d_in[8];
    const float* bv = (const float*)d_in[9];
    const float* Wo = (const float*)d_in[10];
    const float* bo = (const float*)d_in[11];
    float* out = (float*)d_out;

    char* ws = (char*)d_ws;
    ushort* Wqbf  = (ushort*)(ws + 0);                  // 512 KB
    ushort* Wobf  = (ushort*)(ws + 524288u);            // 512 KB
    float*  WkT   = (float*)(ws + (1u << 20));          // 1 MB
    float*  WvT   = (float*)(ws + (2u << 20));          // 1 MB
    float*  kproj = (float*)(ws + (3u << 20));          // 256 KB
    float*  vproj = (float*)(ws + (3u << 20) + 262144u);
    ushort* qbf   = (ushort*)(ws + (4u << 20));         // 48 MB (49152 x 512 bf16)
    ushort* xbf   = (ushort*)(ws + 54525952u);          // 8 MB (8192 x 512 bf16)

    convert2<<<dim3(256, 2), 256, 0, stream>>>(Wq, Wo, Wqbf, Wobf);
    transpose2<<<dim3(16, 16, 2), dim3(32, 8), 0, stream>>>(Wk, Wv, WkT, WvT);

    kv_proj<<<B_ * S_, 512, 0, stream>>>(key, value, WkT, WvT, bk, bv, kproj, vproj);

    // Q projection: M = 49152 rows (b,t,c), fp32 A with PERM, bf16 out
    gemm_mfma<1, 0, 1><<<1536, 256, 0, stream>>>(query, Wqbf, bq, qbf, 384);

    // fused q1_mean + stage1 + stage2 -> x (bf16)
    fused_attn<<<B_ * T_, 64, 0, stream>>>(qbf, kproj, vproj, mask, xbf);

    // output projection: M = 8192, bf16 A (global_load_lds both operands), fp32 out
    gemm_mfma<0, 1, 0><<<256, 256, 0, stream>>>(xbf, Wobf, bo, out, 64);

    (void)in_sizes; (void)n_in; (void)out_size; (void)ws_size;
}